// Round 4
// baseline (232.802 us; speedup 1.0000x reference)
//
#include <hip/hip_runtime.h>

// Inverse 2x2 wavelet (Haar-style) reconstruction.
// x: (8, 16, 512, 512) f32, channels [0:4]=lls, [4:8]=hls, [8:12]=lhs, [12:16]=hhs
// out: (8, 4, 1024, 1024) f32
// out[b,c,2i+di,2j+dj] = g0[dj]*(g0[di]*lls + g1[di]*hls) + g1[dj]*(g0[di]*lhs + g1[di]*hhs)
//
// Experiment ledger (kernel-slice estimates; headline = slice + ~147 us fills):
//   R0: NT/NT, f4 loads, SPARSE stores, 2M one-shot threads      -> ~83 us
//   R1: NT/NT, f2 loads, DENSE  stores, 4M one-shot threads      -> ~78 us (best)
//   R2: normal/normal, R1 mapping                                 -> 84 us (measured)
//       counters: FETCH 64 MiB (half input L3-resident), VALU 5%,
//       occ 66%, conflicts 0 -> latency-bound at 30% HBM peak
//   R3: normal loads/NT stores, 2x per-wave MLP                   -> ~83 us (MLP null)
//
// Conclusion: NT/NT + dense mapping is the flag/mapping optimum; per-wave
// MLP is null -> per-CU outstanding-request window is the limiter.
// THIS ROUND's single variable vs R1: PERSISTENT grid-stride structure
// (the m13 copy-bench structure that reaches 6.3 TB/s on this same mixed
// R+W pattern). 2048 blocks = exactly 32 resident waves/CU, launched once;
// 8 items/thread with a depth-2 software pipeline keeps the CU's memory
// request window continuously full, no wave churn, ~zero addr VALU per
// iteration (item stride 2^19 -> jg,i loop-invariant; pointers += const).

using f2 = __attribute__((ext_vector_type(2))) float;
using f4 = __attribute__((ext_vector_type(4))) float;

__global__ __launch_bounds__(256) void FreTransferInv_kernel(
    const float* __restrict__ x,
    const float* __restrict__ g0,
    const float* __restrict__ g1,
    float* __restrict__ out)
{
    const float g00 = g0[0], g01 = g0[1];
    const float g10 = g1[0], g11 = g1[1];

    // 2048 blocks * 256 threads = 524,288 resident threads; 8 items each.
    const int tid = blockIdx.x * 256 + threadIdx.x;   // 0..524287
    const int jg  = tid & 255;          // input column pair (loop-invariant)
    const int i   = (tid >> 8) & 511;   // input row        (loop-invariant)
    const int bc0 = tid >> 17;          // 0..3; item k has bc = bc0 + 4k

    const size_t plane = 512 * 512;
    // item k: input channel = 16k + bc0 (b=k, c=bc0), so base += 16*plane/step
    const float* pin  = x + ((size_t)bc0 * 512 + (size_t)i) * 512 + (size_t)jg * 2;
    float*       pout = out + ((size_t)bc0 * 1024 + (size_t)(2 * i)) * 1024
                            + (size_t)jg * 4;
    const size_t in_step  = (size_t)16 * plane;        // +16 MiB/4B per item
    const size_t out_step = (size_t)4 * 1024 * 1024;   // bc += 4 per item

    // ---- depth-2 software pipeline over 8 items ----
    f2 a0 = __builtin_nontemporal_load((const f2*)(pin));
    f2 a1 = __builtin_nontemporal_load((const f2*)(pin + 4 * plane));
    f2 a2 = __builtin_nontemporal_load((const f2*)(pin + 8 * plane));
    f2 a3 = __builtin_nontemporal_load((const f2*)(pin + 12 * plane));

#pragma unroll
    for (int k = 0; k < 8; ++k) {
        f2 b0, b1, b2, b3;
        if (k < 7) {
            const float* pn = pin + in_step;
            b0 = __builtin_nontemporal_load((const f2*)(pn));
            b1 = __builtin_nontemporal_load((const f2*)(pn + 4 * plane));
            b2 = __builtin_nontemporal_load((const f2*)(pn + 8 * plane));
            b3 = __builtin_nontemporal_load((const f2*)(pn + 12 * plane));
        }

        f4 ve, vo;  // even / odd output row (4 cols each)
#pragma unroll
        for (int kk = 0; kk < 2; ++kk) {
            const float L  = a0[kk];
            const float H  = a1[kk];
            const float Lh = a2[kk];
            const float Hh = a3[kk];
            const float lo_e = g00 * L  + g10 * H;
            const float lo_o = g01 * L  + g11 * H;
            const float hi_e = g00 * Lh + g10 * Hh;
            const float hi_o = g01 * Lh + g11 * Hh;
            ve[2 * kk]     = g00 * lo_e + g10 * hi_e;
            ve[2 * kk + 1] = g01 * lo_e + g11 * hi_e;
            vo[2 * kk]     = g00 * lo_o + g10 * hi_o;
            vo[2 * kk + 1] = g01 * lo_o + g11 * hi_o;
        }

        __builtin_nontemporal_store(ve, (f4*)(pout));
        __builtin_nontemporal_store(vo, (f4*)(pout + 1024));

        if (k < 7) {
            a0 = b0; a1 = b1; a2 = b2; a3 = b3;
            pin  += in_step;
            pout += out_step;
        }
    }
}

extern "C" void kernel_launch(void* const* d_in, const int* in_sizes, int n_in,
                              void* d_out, int out_size, void* d_ws, size_t ws_size,
                              hipStream_t stream) {
    const float* x  = (const float*)d_in[0];
    const float* g0 = (const float*)d_in[1];
    const float* g1 = (const float*)d_in[2];
    float* out = (float*)d_out;

    // 2048 blocks -> exactly 8 blocks/CU * 4 waves = 32 resident waves/CU
    FreTransferInv_kernel<<<2048, 256, 0, stream>>>(x, g0, g1, out);
}

// Round 6
// 223.487 us; speedup vs baseline: 1.0417x; 1.0417x over previous
//
#include <hip/hip_runtime.h>

// Inverse 2x2 wavelet (Haar-style) reconstruction.
// x: (8, 16, 512, 512) f32, channels [0:4]=lls, [4:8]=hls, [8:12]=lhs, [12:16]=hhs
// out: (8, 4, 1024, 1024) f32
// out[b,c,2i+di,2j+dj] = g0[dj]*(g0[di]*lls + g1[di]*hls) + g1[dj]*(g0[di]*lhs + g1[di]*hhs)
//
// Experiment ledger (kernel-slice estimates; headline = slice + ~147 us fills):
//   R0: NT/NT, f4 ld (16B), SPARSE st, 2M threads          -> ~83 us
//   R1: NT/NT, f2 ld ( 8B), DENSE  st, 4M threads          -> ~78 us (best)
//   R2: norm/norm, R1 mapping: FETCH 64MiB (half input L3-resident),
//       VALU 5%, occ 66%, conflicts 0 -> latency-limited at ~3.2 TB/s fabric
//   R3: norm ld/NT st, 2x per-wave MLP                      -> ~83 us (MLP null)
//   R4: R1 + persistent 2048-block grid-stride              -> ~86 us (null/neg)
//   R5: f4 ld + dense st via XOR-swizzled LDS: WRONG (wq|p collided for odd
//       lanes -> slot overwrite). Swizzle was also unnecessary: natural
//       layout is 2-way on write (free, m136) and conflict-free on read.
//
// THIS ROUND: R5's idea, correct + simple. 16 B/lane NT loads (copy-parity
// with m13's 6.3 TB/s dwordx4 benchmark) AND 16 B/lane fully dense NT stores,
// reconciled via natural-layout LDS redistribution:
//   lane l computes wave-local output cols [8l, 8l+8) x {even,odd} rows
//   = pieces 2l, 2l+1 of each row (piece = 4 cols = one f4);
//   writes them to lx[wave][row][piece];
//   reads back pieces l and 64+l of each row -> 4 dense 16 B stores
//   (lane stride 16 B, 1 KiB/wave/instruction, same pattern R1 proved out).

using f4 = __attribute__((ext_vector_type(4))) float;

__global__ __launch_bounds__(256) void FreTransferInv_kernel(
    const float* __restrict__ x,
    const float* __restrict__ g0,
    const float* __restrict__ g1,
    float* __restrict__ out)
{
    const float g00 = g0[0], g01 = g0[1];
    const float g10 = g1[0], g11 = g1[1];

    // total threads = 8*4*512*128 = 2,097,152 (one group of 4 input cols each)
    const int tid = blockIdx.x * 256 + threadIdx.x;

    const int jg = tid & 127;          // input col-group (4 cols)
    const int i  = (tid >> 7) & 511;   // input row (wave-uniform)
    const int bc = tid >> 16;          // b*4 + c, 0..31 (wave-uniform)
    const int b  = bc >> 2;
    const int c  = bc & 3;

    const size_t plane = 512 * 512;
    const size_t in_base =
        ((size_t)(b * 16 + c) * 512 + (size_t)i) * 512 + (size_t)jg * 4;

    // 16 B/lane NT loads: 1 KiB per wave per instruction (copy-parity)
    const f4 lls = __builtin_nontemporal_load((const f4*)(x + in_base));
    const f4 hls = __builtin_nontemporal_load((const f4*)(x + in_base + 4 * plane));
    const f4 lhs = __builtin_nontemporal_load((const f4*)(x + in_base + 8 * plane));
    const f4 hhs = __builtin_nontemporal_load((const f4*)(x + in_base + 12 * plane));

    float e[8], o[8];  // even / odd output row, 8 cols
#pragma unroll
    for (int k = 0; k < 4; ++k) {
        const float L  = lls[k];
        const float H  = hls[k];
        const float Lh = lhs[k];
        const float Hh = hhs[k];
        const float lo_e = g00 * L  + g10 * H;
        const float lo_o = g01 * L  + g11 * H;
        const float hi_e = g00 * Lh + g10 * Hh;
        const float hi_o = g01 * Lh + g11 * Hh;
        e[2 * k]     = g00 * lo_e + g10 * hi_e;
        e[2 * k + 1] = g01 * lo_e + g11 * hi_e;
        o[2 * k]     = g00 * lo_o + g10 * hi_o;
        o[2 * k + 1] = g01 * lo_o + g11 * hi_o;
    }

    // ---- intra-wave LDS redistribution to the dense store assignment ----
    // Natural layout [wave][row][piece]. Write: lane l -> pieces 2l,2l+1
    // (32 B lane stride = 2-way bank conflict = free). Read: lane l ->
    // pieces l and 64+l (16 B contiguous = conflict-free). 16 KiB/block.
    __shared__ f4 lx[4][2][128];
    const int lane = threadIdx.x & 63;
    const int wv   = threadIdx.x >> 6;

    lx[wv][0][2 * lane]     = f4{ e[0], e[1], e[2], e[3] };
    lx[wv][0][2 * lane + 1] = f4{ e[4], e[5], e[6], e[7] };
    lx[wv][1][2 * lane]     = f4{ o[0], o[1], o[2], o[3] };
    lx[wv][1][2 * lane + 1] = f4{ o[4], o[5], o[6], o[7] };

    __syncthreads();

    const f4 vAe = lx[wv][0][lane];
    const f4 vBe = lx[wv][0][64 + lane];
    const f4 vAo = lx[wv][1][lane];
    const f4 vBo = lx[wv][1][64 + lane];

    // Wave covers output cols [8*jg0*1, 8*jg0 + 512) where jg0 = jg & 64
    // (lanes are consecutive jg within the wave: jg = jg0 + lane).
    const int jg0 = jg & 64;
    const size_t rowE = ((size_t)bc * 1024 + (size_t)(2 * i)) * 1024
                      + (size_t)jg0 * 8 + (size_t)(4 * lane);

    __builtin_nontemporal_store(vAe, (f4*)(out + rowE));
    __builtin_nontemporal_store(vBe, (f4*)(out + rowE + 256));
    __builtin_nontemporal_store(vAo, (f4*)(out + rowE + 1024));
    __builtin_nontemporal_store(vBo, (f4*)(out + rowE + 1024 + 256));
}

extern "C" void kernel_launch(void* const* d_in, const int* in_sizes, int n_in,
                              void* d_out, int out_size, void* d_ws, size_t ws_size,
                              hipStream_t stream) {
    const float* x  = (const float*)d_in[0];
    const float* g0 = (const float*)d_in[1];
    const float* g1 = (const float*)d_in[2];
    float* out = (float*)d_out;

    // 8*4*512*128 threads / 256 per block
    const int total_threads = 8 * 4 * 512 * 128;
    const int blocks = total_threads / 256;
    FreTransferInv_kernel<<<blocks, 256, 0, stream>>>(x, g0, g1, out);
}